// Round 2
// baseline (880.162 us; speedup 1.0000x reference)
//
#include <hip/hip_runtime.h>
#include <math.h>

// ---------------------------------------------------------------------------
// Problem constants (from reference): H=W=512, CELL=8, P=16, GX=GY=64, NGH=32
// nodes = 4*32*32 = 4096; patch = 16x16 centered on 8x8 cell (offset -4).
// conv1: 3x3 1->40; conv2: 3x3 40->40; dense1: 10240->6;
// edge MLP 13->5->5->5->10; node MLP 17->5->5->5->10; out 10->2 -> CE loss.
// ---------------------------------------------------------------------------

static __device__ __forceinline__ float diff_round(float x) {
    const float TP = 6.2831853071795864769f;
    return x - sinf(x * TP) / TP;
}

template<int IN, int OUT>
static __device__ __forceinline__ void mlp_layer(const float* in,
                                                 const float* __restrict__ w,
                                                 const float* __restrict__ b,
                                                 float* out, bool do_relu) {
#pragma unroll
    for (int j = 0; j < OUT; ++j) {
        float a = b[j];
#pragma unroll
        for (int i = 0; i < IN; ++i) a = fmaf(in[i], w[i * OUT + j], a);
        out[j] = do_relu ? fmaxf(a, 0.f) : a;
    }
}

// ---------------------------------------------------------------------------
// Kernel 1: per-patch fused token-build + conv1 + conv2 + dense1 (+ lsv, agg=0)
// block = 256 threads (one per pixel), grid = 4096 (one per node/patch)
// LDS: p[18*18] padded input patch, x1[10][324][4] padded conv1 output
//      (layout [ci-group][pixel][4] so conv2 reads are consecutive float4s)
//
// __launch_bounds__(256, 2): min 2 waves/EU -> 256-VGPR budget. Without the
// second arg the compiler targeted a high-occupancy budget (68 VGPRs) and
// spilled acc[40]/a1[40] to scratch: rocprof R1 showed WRITE_SIZE=279 MB
// (vs ~0.27 MB of logical output) and VALUBusy=29%. LDS (53.7 KB) caps
// occupancy at ~3 blocks/CU anyway, so the register headroom is free.
// ---------------------------------------------------------------------------
__global__ __launch_bounds__(256, 2) void k_patch(
    const float* __restrict__ img, const float* __restrict__ lab,
    const float* __restrict__ msk,
    const float* __restrict__ w1, const float* __restrict__ b1,
    const float* __restrict__ w2, const float* __restrict__ b2,
    const float* __restrict__ d1w, const float* __restrict__ d1b,
    float* __restrict__ nodes, float* __restrict__ lsv, float* __restrict__ agg)
{
    __shared__ float p[18 * 18];
    __shared__ float x1[10 * 324 * 4];
    __shared__ float red[4][2];
    __shared__ float wsum[4][6];

    const int n = blockIdx.x;
    const int t = threadIdx.x;
    const int g = n >> 10, cell = n & 1023;
    const int gi = cell >> 5, gj = cell & 31;
    const int sx = g & 1, sy = g >> 1;           // SHIFTS order (0,0),(1,0),(0,1),(1,1)
    const int gx = sx + 2 * gi, gy = sy + 2 * gj;
    const int px0 = gx * 8 - 4, py0 = gy * 8 - 4;
    const float cid = (float)(gx * 64 + gy);

    const int u = t >> 4, v = t & 15;
    const int lane = t & 63, wv = t >> 6;

    // ---- phase 0: zero LDS (conv zero-padding lives in the borders) ----
    for (int i = t; i < 10 * 324 * 4; i += 256) x1[i] = 0.f;
    for (int i = t; i < 324; i += 256) p[i] = 0.f;
    __syncthreads();

    // ---- phase 1: token + label stats ----
    const int r = px0 + u, c = py0 + v;
    const bool inr = (r >= 0) && (r < 512) && (c >= 0) && (c < 512);
    const float m  = inr ? msk[r * 512 + c] : -1.0f;
    const float f  = (m == cid) ? 1.f : 0.f;
    const float iv = inr ? img[r * 512 + c] : 0.f;
    const float lv = inr ? lab[r * 512 + c] : 0.f;
    p[(u + 1) * 18 + (v + 1)] = iv * f;

    float sf = f, slf = lv * f;
    for (int off = 32; off; off >>= 1) {
        sf  += __shfl_down(sf,  off);
        slf += __shfl_down(slf, off);
    }
    if (lane == 0) { red[wv][0] = sf; red[wv][1] = slf; }
    __syncthreads();

    // ---- phase 2: conv1 (1->40) into padded LDS; also lsv + agg zero ----
    {
        float nbv[9];
#pragma unroll
        for (int ky = 0; ky < 3; ++ky)
#pragma unroll
            for (int kx = 0; kx < 3; ++kx)
                nbv[ky * 3 + kx] = p[(u + ky) * 18 + (v + kx)];
        float a1[40];
#pragma unroll
        for (int co = 0; co < 40; ++co) a1[co] = b1[co];
#pragma unroll
        for (int k = 0; k < 9; ++k) {
            const float xv = nbv[k];
#pragma unroll
            for (int co = 0; co < 40; ++co)
                a1[co] = fmaf(xv, w1[k * 40 + co], a1[co]);
        }
        const int pix = (u + 1) * 18 + (v + 1);
#pragma unroll
        for (int cg = 0; cg < 10; ++cg) {
            float4 wq;
            wq.x = fmaxf(a1[cg * 4 + 0], 0.f);
            wq.y = fmaxf(a1[cg * 4 + 1], 0.f);
            wq.z = fmaxf(a1[cg * 4 + 2], 0.f);
            wq.w = fmaxf(a1[cg * 4 + 3], 0.f);
            *(float4*)&x1[(cg * 324 + pix) * 4] = wq;
        }
    }
    if (t == 0) {
        const float SF = red[0][0] + red[1][0] + red[2][0] + red[3][0];
        const float SL = red[0][1] + red[1][1] + red[2][1] + red[3][1];
        lsv[n] = diff_round(diff_round(SL / (SF + 1e-8f)));
    }
    if (t < 10) agg[n * 10 + t] = 0.f;   // zero segment-sum target for kernel 2
    __syncthreads();

    // ---- phase 3: conv2 (40->40), 40 accumulators per thread ----
    float acc[40];
#pragma unroll
    for (int co = 0; co < 40; ++co) acc[co] = b2[co];

    for (int ky = 0; ky < 3; ++ky) {
        for (int kx = 0; kx < 3; ++kx) {
            const int nb = (u + ky) * 18 + (v + kx);
            const int k  = ky * 3 + kx;
            for (int cg = 0; cg < 10; ++cg) {
                const float4 xv = *(const float4*)&x1[(cg * 324 + nb) * 4];
                const float* __restrict__ wr = w2 + (k * 40 + cg * 4) * 40;
#pragma unroll
                for (int ci = 0; ci < 4; ++ci) {
                    const float xs = (&xv.x)[ci];
#pragma unroll
                    for (int co = 0; co < 40; ++co)
                        acc[co] = fmaf(xs, wr[ci * 40 + co], acc[co]);
                }
            }
        }
    }

    // ---- phase 4: relu + dense1 partials (pixel-local slice of the 10240x6) ----
    float a6[6] = {0.f, 0.f, 0.f, 0.f, 0.f, 0.f};
    {
        const int pf = u * 16 + v;               // unpadded flat pixel 0..255
        const float* __restrict__ dw = d1w + pf * 240;   // 40 co * 6 outputs
#pragma unroll 8
        for (int co = 0; co < 40; ++co) {
            const float a = fmaxf(acc[co], 0.f);
#pragma unroll
            for (int k = 0; k < 6; ++k)
                a6[k] = fmaf(a, dw[co * 6 + k], a6[k]);
        }
    }
    for (int off = 32; off; off >>= 1) {
#pragma unroll
        for (int k = 0; k < 6; ++k) a6[k] += __shfl_down(a6[k], off);
    }
    if (lane == 0) {
#pragma unroll
        for (int k = 0; k < 6; ++k) wsum[wv][k] = a6[k];
    }
    __syncthreads();
    if (t < 6) {
        const float s = wsum[0][t] + wsum[1][t] + wsum[2][t] + wsum[3][t] + d1b[t];
        nodes[n * 6 + t] = fmaxf(s, 0.f);
    }
}

// ---------------------------------------------------------------------------
// Kernel 2: edge MLP + atomic segment-sum into agg
// ---------------------------------------------------------------------------
__global__ __launch_bounds__(256) void k_edge(
    const float* __restrict__ nodes, const int* __restrict__ snd,
    const int* __restrict__ rcv, int E,
    const float* __restrict__ we0, const float* __restrict__ be0,
    const float* __restrict__ we1, const float* __restrict__ be1,
    const float* __restrict__ we2, const float* __restrict__ be2,
    const float* __restrict__ we3, const float* __restrict__ be3,
    float* __restrict__ agg)
{
    const int e = blockIdx.x * 256 + threadIdx.x;
    if (e >= E) return;
    const int s = snd[e], r = rcv[e];
    float in[13];
#pragma unroll
    for (int i = 0; i < 6; ++i) in[i]     = nodes[s * 6 + i];
#pragma unroll
    for (int i = 0; i < 6; ++i) in[6 + i] = nodes[r * 6 + i];
    in[12] = 1.f;
    float h0[5], h1[5], h2[5], o[10];
    mlp_layer<13, 5>(in, we0, be0, h0, true);
    mlp_layer<5, 5>(h0, we1, be1, h1, true);
    mlp_layer<5, 5>(h1, we2, be2, h2, true);
    mlp_layer<5, 10>(h2, we3, be3, o, false);
#pragma unroll
    for (int j = 0; j < 10; ++j) atomicAdd(&agg[r * 10 + j], o[j]);
}

// ---------------------------------------------------------------------------
// Kernel 3: node MLP + logits + softmax cross-entropy
// ---------------------------------------------------------------------------
__global__ __launch_bounds__(256) void k_node(
    const float* __restrict__ nodes, const float* __restrict__ agg,
    const float* __restrict__ lsv,
    const float* __restrict__ wn0, const float* __restrict__ bn0,
    const float* __restrict__ wn1, const float* __restrict__ bn1,
    const float* __restrict__ wn2, const float* __restrict__ bn2,
    const float* __restrict__ wn3, const float* __restrict__ bn3,
    const float* __restrict__ wout, const float* __restrict__ bout,
    float* __restrict__ out, int N)
{
    const int n = blockIdx.x * 256 + threadIdx.x;
    if (n >= N) return;
    float in[17];
#pragma unroll
    for (int i = 0; i < 6; ++i)  in[i]     = nodes[n * 6 + i];
#pragma unroll
    for (int i = 0; i < 10; ++i) in[6 + i] = agg[n * 10 + i];
    in[16] = 1.f;
    float h0[5], h1[5], h2[5], o[10];
    mlp_layer<17, 5>(in, wn0, bn0, h0, true);
    mlp_layer<5, 5>(h0, wn1, bn1, h1, true);
    mlp_layer<5, 5>(h1, wn2, bn2, h2, true);
    mlp_layer<5, 10>(h2, wn3, bn3, o, false);

    float l0 = bout[0], l1 = bout[1];
#pragma unroll
    for (int i = 0; i < 10; ++i) {
        l0 = fmaf(o[i], wout[i * 2 + 0], l0);
        l1 = fmaf(o[i], wout[i * 2 + 1], l1);
    }
    const float mx  = fmaxf(l0, l1);
    const float e0  = expf(l0 - mx), e1 = expf(l1 - mx);
    const float lse = mx + logf(e0 + e1);
    const float sv  = lsv[n];
    out[n] = -((1.f - sv) * (l0 - lse) + sv * (l1 - lse));
}

// ---------------------------------------------------------------------------
extern "C" void kernel_launch(void* const* d_in, const int* in_sizes, int n_in,
                              void* d_out, int out_size, void* d_ws, size_t ws_size,
                              hipStream_t stream) {
    (void)n_in; (void)ws_size;
    const float* img = (const float*)d_in[0];
    const float* lab = (const float*)d_in[1];
    const float* msk = (const float*)d_in[2];
    const float* w1  = (const float*)d_in[3];
    const float* b1  = (const float*)d_in[4];
    const float* w2  = (const float*)d_in[5];
    const float* b2  = (const float*)d_in[6];
    const float* d1w = (const float*)d_in[7];
    const float* d1b = (const float*)d_in[8];
    const float* we0 = (const float*)d_in[9],  *be0 = (const float*)d_in[10];
    const float* we1 = (const float*)d_in[11], *be1 = (const float*)d_in[12];
    const float* we2 = (const float*)d_in[13], *be2 = (const float*)d_in[14];
    const float* we3 = (const float*)d_in[15], *be3 = (const float*)d_in[16];
    const float* wn0 = (const float*)d_in[17], *bn0 = (const float*)d_in[18];
    const float* wn1 = (const float*)d_in[19], *bn1 = (const float*)d_in[20];
    const float* wn2 = (const float*)d_in[21], *bn2 = (const float*)d_in[22];
    const float* wn3 = (const float*)d_in[23], *bn3 = (const float*)d_in[24];
    const float* wout = (const float*)d_in[25], *bout = (const float*)d_in[26];
    const int* snd = (const int*)d_in[27];
    const int* rcv = (const int*)d_in[28];
    const int E = in_sizes[27];
    const int N = out_size;              // 4096 nodes

    float* ws    = (float*)d_ws;
    float* nodes = ws;                   // N*6
    float* lsvb  = ws + (size_t)N * 6;   // N
    float* agg   = ws + (size_t)N * 7;   // N*10 (zeroed inside k_patch)
    float* out   = (float*)d_out;

    k_patch<<<N, 256, 0, stream>>>(img, lab, msk, w1, b1, w2, b2, d1w, d1b,
                                   nodes, lsvb, agg);
    k_edge<<<(E + 255) / 256, 256, 0, stream>>>(nodes, snd, rcv, E,
                                                we0, be0, we1, be1, we2, be2,
                                                we3, be3, agg);
    k_node<<<(N + 255) / 256, 256, 0, stream>>>(nodes, agg, lsvb,
                                                wn0, bn0, wn1, bn1, wn2, bn2,
                                                wn3, bn3, wout, bout, out, N);
}

// Round 3
// 709.747 us; speedup vs baseline: 1.2401x; 1.2401x over previous
//
#include <hip/hip_runtime.h>
#include <math.h>

// ---------------------------------------------------------------------------
// Problem constants (from reference): H=W=512, CELL=8, P=16, GX=GY=64, NGH=32
// nodes = 4*32*32 = 4096; patch = 16x16 centered on 8x8 cell (offset -4).
// conv1: 3x3 1->40; conv2: 3x3 40->40; dense1: 10240->6;
// edge MLP 13->5->5->5->10; node MLP 17->5->5->5->10; out 10->2 -> CE loss.
// ---------------------------------------------------------------------------

static __device__ __forceinline__ float diff_round(float x) {
    const float TP = 6.2831853071795864769f;
    return x - sinf(x * TP) / TP;
}

template<int IN, int OUT>
static __device__ __forceinline__ void mlp_layer(const float* in,
                                                 const float* __restrict__ w,
                                                 const float* __restrict__ b,
                                                 float* out, bool do_relu) {
#pragma unroll
    for (int j = 0; j < OUT; ++j) {
        float a = b[j];
#pragma unroll
        for (int i = 0; i < IN; ++i) a = fmaf(in[i], w[i * OUT + j], a);
        out[j] = do_relu ? fmaxf(a, 0.f) : a;
    }
}

// ---------------------------------------------------------------------------
// Kernel 1: per-patch fused token-build + conv1 + conv2 + dense1 (+ lsv, agg=0)
// block = 256 threads (one per pixel), grid = 4096 (one per node/patch)
// LDS: p[18*18] padded input patch, x1[10][324][4] padded conv1 output
//      (layout [ci-group][pixel][4] so conv2 reads are consecutive float4s)
//
// CRITICAL (R2 post-mortem): every access to acc[]/a1[] must be
// CONSTANT-indexed — a single runtime-indexed access (e.g. a partially
// unrolled loop, "#pragma unroll 8") defeats SROA and demotes the whole
// array to scratch for the kernel's lifetime. R1/R2 rocprof: VGPR=68,
// WRITE_SIZE=279 MB (scratch write-back), VALUBusy=29%. All acc loops are
// therefore FULLY unrolled. __launch_bounds__(256,2) gives the 256-VGPR
// budget the promoted arrays need; LDS caps occupancy at ~2-3 blocks/CU.
// ---------------------------------------------------------------------------
__global__ __launch_bounds__(256, 2) void k_patch(
    const float* __restrict__ img, const float* __restrict__ lab,
    const float* __restrict__ msk,
    const float* __restrict__ w1, const float* __restrict__ b1,
    const float* __restrict__ w2, const float* __restrict__ b2,
    const float* __restrict__ d1w, const float* __restrict__ d1b,
    float* __restrict__ nodes, float* __restrict__ lsv, float* __restrict__ agg)
{
    __shared__ float p[18 * 18];
    __shared__ float x1[10 * 324 * 4];
    __shared__ float red[4][2];
    __shared__ float wsum[4][6];

    const int n = blockIdx.x;
    const int t = threadIdx.x;
    const int g = n >> 10, cell = n & 1023;
    const int gi = cell >> 5, gj = cell & 31;
    const int sx = g & 1, sy = g >> 1;           // SHIFTS order (0,0),(1,0),(0,1),(1,1)
    const int gx = sx + 2 * gi, gy = sy + 2 * gj;
    const int px0 = gx * 8 - 4, py0 = gy * 8 - 4;
    const float cid = (float)(gx * 64 + gy);

    const int u = t >> 4, v = t & 15;
    const int lane = t & 63, wv = t >> 6;

    // ---- phase 0: zero LDS (conv zero-padding lives in the borders) ----
    for (int i = t; i < 10 * 324 * 4; i += 256) x1[i] = 0.f;
    for (int i = t; i < 324; i += 256) p[i] = 0.f;
    __syncthreads();

    // ---- phase 1: token + label stats ----
    const int r = px0 + u, c = py0 + v;
    const bool inr = (r >= 0) && (r < 512) && (c >= 0) && (c < 512);
    const float m  = inr ? msk[r * 512 + c] : -1.0f;
    const float f  = (m == cid) ? 1.f : 0.f;
    const float iv = inr ? img[r * 512 + c] : 0.f;
    const float lv = inr ? lab[r * 512 + c] : 0.f;
    p[(u + 1) * 18 + (v + 1)] = iv * f;

    float sf = f, slf = lv * f;
    for (int off = 32; off; off >>= 1) {
        sf  += __shfl_down(sf,  off);
        slf += __shfl_down(slf, off);
    }
    if (lane == 0) { red[wv][0] = sf; red[wv][1] = slf; }
    __syncthreads();

    // ---- phase 2: conv1 (1->40) into padded LDS; also lsv + agg zero ----
    {
        float nbv[9];
#pragma unroll
        for (int ky = 0; ky < 3; ++ky)
#pragma unroll
            for (int kx = 0; kx < 3; ++kx)
                nbv[ky * 3 + kx] = p[(u + ky) * 18 + (v + kx)];
        float a1[40];
#pragma unroll
        for (int co = 0; co < 40; ++co) a1[co] = b1[co];
#pragma unroll
        for (int k = 0; k < 9; ++k) {
            const float xv = nbv[k];
#pragma unroll
            for (int co = 0; co < 40; ++co)
                a1[co] = fmaf(xv, w1[k * 40 + co], a1[co]);
        }
        const int pix = (u + 1) * 18 + (v + 1);
#pragma unroll
        for (int cg = 0; cg < 10; ++cg) {
            float4 wq;
            wq.x = fmaxf(a1[cg * 4 + 0], 0.f);
            wq.y = fmaxf(a1[cg * 4 + 1], 0.f);
            wq.z = fmaxf(a1[cg * 4 + 2], 0.f);
            wq.w = fmaxf(a1[cg * 4 + 3], 0.f);
            *(float4*)&x1[(cg * 324 + pix) * 4] = wq;
        }
    }
    if (t == 0) {
        const float SF = red[0][0] + red[1][0] + red[2][0] + red[3][0];
        const float SL = red[0][1] + red[1][1] + red[2][1] + red[3][1];
        lsv[n] = diff_round(diff_round(SL / (SF + 1e-8f)));
    }
    if (t < 10) agg[n * 10 + t] = 0.f;   // zero segment-sum target for kernel 2
    __syncthreads();

    // ---- phase 3: conv2 (40->40), 40 accumulators per thread ----
    float acc[40];
#pragma unroll
    for (int co = 0; co < 40; ++co) acc[co] = b2[co];

    for (int ky = 0; ky < 3; ++ky) {
        for (int kx = 0; kx < 3; ++kx) {
            const int nb = (u + ky) * 18 + (v + kx);
            const int k  = ky * 3 + kx;
            for (int cg = 0; cg < 10; ++cg) {
                const float4 xv = *(const float4*)&x1[(cg * 324 + nb) * 4];
                const float* __restrict__ wr = w2 + (k * 40 + cg * 4) * 40;
#pragma unroll
                for (int ci = 0; ci < 4; ++ci) {
                    const float xs = (&xv.x)[ci];
#pragma unroll
                    for (int co = 0; co < 40; ++co)
                        acc[co] = fmaf(xs, wr[ci * 40 + co], acc[co]);
                }
            }
        }
    }

    // ---- phase 4: relu + dense1 partials (pixel-local slice of the 10240x6) ----
    // FULLY unrolled: runtime-indexed acc[co] here is what sank R1/R2.
    float a6[6] = {0.f, 0.f, 0.f, 0.f, 0.f, 0.f};
    {
        const int pf = u * 16 + v;               // unpadded flat pixel 0..255
        const float* __restrict__ dw = d1w + pf * 240;   // 40 co * 6 outputs
#pragma unroll
        for (int co = 0; co < 40; ++co) {
            const float a = fmaxf(acc[co], 0.f);
#pragma unroll
            for (int k = 0; k < 6; ++k)
                a6[k] = fmaf(a, dw[co * 6 + k], a6[k]);
        }
    }
    for (int off = 32; off; off >>= 1) {
#pragma unroll
        for (int k = 0; k < 6; ++k) a6[k] += __shfl_down(a6[k], off);
    }
    if (lane == 0) {
#pragma unroll
        for (int k = 0; k < 6; ++k) wsum[wv][k] = a6[k];
    }
    __syncthreads();
    if (t < 6) {
        const float s = wsum[0][t] + wsum[1][t] + wsum[2][t] + wsum[3][t] + d1b[t];
        nodes[n * 6 + t] = fmaxf(s, 0.f);
    }
}

// ---------------------------------------------------------------------------
// Kernel 2: edge MLP + atomic segment-sum into agg
// ---------------------------------------------------------------------------
__global__ __launch_bounds__(256) void k_edge(
    const float* __restrict__ nodes, const int* __restrict__ snd,
    const int* __restrict__ rcv, int E,
    const float* __restrict__ we0, const float* __restrict__ be0,
    const float* __restrict__ we1, const float* __restrict__ be1,
    const float* __restrict__ we2, const float* __restrict__ be2,
    const float* __restrict__ we3, const float* __restrict__ be3,
    float* __restrict__ agg)
{
    const int e = blockIdx.x * 256 + threadIdx.x;
    if (e >= E) return;
    const int s = snd[e], r = rcv[e];
    float in[13];
#pragma unroll
    for (int i = 0; i < 6; ++i) in[i]     = nodes[s * 6 + i];
#pragma unroll
    for (int i = 0; i < 6; ++i) in[6 + i] = nodes[r * 6 + i];
    in[12] = 1.f;
    float h0[5], h1[5], h2[5], o[10];
    mlp_layer<13, 5>(in, we0, be0, h0, true);
    mlp_layer<5, 5>(h0, we1, be1, h1, true);
    mlp_layer<5, 5>(h1, we2, be2, h2, true);
    mlp_layer<5, 10>(h2, we3, be3, o, false);
#pragma unroll
    for (int j = 0; j < 10; ++j) atomicAdd(&agg[r * 10 + j], o[j]);
}

// ---------------------------------------------------------------------------
// Kernel 3: node MLP + logits + softmax cross-entropy
// ---------------------------------------------------------------------------
__global__ __launch_bounds__(256) void k_node(
    const float* __restrict__ nodes, const float* __restrict__ agg,
    const float* __restrict__ lsv,
    const float* __restrict__ wn0, const float* __restrict__ bn0,
    const float* __restrict__ wn1, const float* __restrict__ bn1,
    const float* __restrict__ wn2, const float* __restrict__ bn2,
    const float* __restrict__ wn3, const float* __restrict__ bn3,
    const float* __restrict__ wout, const float* __restrict__ bout,
    float* __restrict__ out, int N)
{
    const int n = blockIdx.x * 256 + threadIdx.x;
    if (n >= N) return;
    float in[17];
#pragma unroll
    for (int i = 0; i < 6; ++i)  in[i]     = nodes[n * 6 + i];
#pragma unroll
    for (int i = 0; i < 10; ++i) in[6 + i] = agg[n * 10 + i];
    in[16] = 1.f;
    float h0[5], h1[5], h2[5], o[10];
    mlp_layer<17, 5>(in, wn0, bn0, h0, true);
    mlp_layer<5, 5>(h0, wn1, bn1, h1, true);
    mlp_layer<5, 5>(h1, wn2, bn2, h2, true);
    mlp_layer<5, 10>(h2, wn3, bn3, o, false);

    float l0 = bout[0], l1 = bout[1];
#pragma unroll
    for (int i = 0; i < 10; ++i) {
        l0 = fmaf(o[i], wout[i * 2 + 0], l0);
        l1 = fmaf(o[i], wout[i * 2 + 1], l1);
    }
    const float mx  = fmaxf(l0, l1);
    const float e0  = expf(l0 - mx), e1 = expf(l1 - mx);
    const float lse = mx + logf(e0 + e1);
    const float sv  = lsv[n];
    out[n] = -((1.f - sv) * (l0 - lse) + sv * (l1 - lse));
}

// ---------------------------------------------------------------------------
extern "C" void kernel_launch(void* const* d_in, const int* in_sizes, int n_in,
                              void* d_out, int out_size, void* d_ws, size_t ws_size,
                              hipStream_t stream) {
    (void)n_in; (void)ws_size;
    const float* img = (const float*)d_in[0];
    const float* lab = (const float*)d_in[1];
    const float* msk = (const float*)d_in[2];
    const float* w1  = (const float*)d_in[3];
    const float* b1  = (const float*)d_in[4];
    const float* w2  = (const float*)d_in[5];
    const float* b2  = (const float*)d_in[6];
    const float* d1w = (const float*)d_in[7];
    const float* d1b = (const float*)d_in[8];
    const float* we0 = (const float*)d_in[9],  *be0 = (const float*)d_in[10];
    const float* we1 = (const float*)d_in[11], *be1 = (const float*)d_in[12];
    const float* we2 = (const float*)d_in[13], *be2 = (const float*)d_in[14];
    const float* we3 = (const float*)d_in[15], *be3 = (const float*)d_in[16];
    const float* wn0 = (const float*)d_in[17], *bn0 = (const float*)d_in[18];
    const float* wn1 = (const float*)d_in[19], *bn1 = (const float*)d_in[20];
    const float* wn2 = (const float*)d_in[21], *bn2 = (const float*)d_in[22];
    const float* wn3 = (const float*)d_in[23], *bn3 = (const float*)d_in[24];
    const float* wout = (const float*)d_in[25], *bout = (const float*)d_in[26];
    const int* snd = (const int*)d_in[27];
    const int* rcv = (const int*)d_in[28];
    const int E = in_sizes[27];
    const int N = out_size;              // 4096 nodes

    float* ws    = (float*)d_ws;
    float* nodes = ws;                   // N*6
    float* lsvb  = ws + (size_t)N * 6;   // N
    float* agg   = ws + (size_t)N * 7;   // N*10 (zeroed inside k_patch)
    float* out   = (float*)d_out;

    k_patch<<<N, 256, 0, stream>>>(img, lab, msk, w1, b1, w2, b2, d1w, d1b,
                                   nodes, lsvb, agg);
    k_edge<<<(E + 255) / 256, 256, 0, stream>>>(nodes, snd, rcv, E,
                                                we0, be0, we1, be1, we2, be2,
                                                we3, be3, agg);
    k_node<<<(N + 255) / 256, 256, 0, stream>>>(nodes, agg, lsvb,
                                                wn0, bn0, wn1, bn1, wn2, bn2,
                                                wn3, bn3, wout, bout, out, N);
}

// Round 4
// 323.933 us; speedup vs baseline: 2.7171x; 2.1910x over previous
//
#include <hip/hip_runtime.h>
#include <math.h>

// ---------------------------------------------------------------------------
// Problem: H=W=512, CELL=8, P=16, NGH=32; nodes = 4*32*32 = 4096 patches 16x16.
// conv1 3x3 1->40 (fp32 VALU); conv2 3x3 40->40 (bf16 MFMA, fp32 acc);
// dense1 10240->6 (fp32); edge MLP 13->5->5->5->10; node MLP 17->5->5->5->10.
//
// R3 post-mortem: conv2 on the fp32 VALU is floor-limited at ~204 us and was
// latency-stalled at 37% busy. Harness threshold (2.17e-2 = 8*eps_bf16*range)
// is bf16-calibrated -> conv2 moves to mfma_f32_16x16x32_bf16 as a per-tap
// im2col GEMM: M=256 pixels, N=40 co (3 tiles of 16), K=40 ci (pad 64, 2 steps).
// Layouts (HW-verified per guide): A[m=lane&15][k=quad*8+j]; B[k=quad*8+j][n=lane&15];
// C/D col=lane&15, row=quad*4+reg.
// x1 LDS: bf16, row stride 56 ushorts (112 B) -> b128 A-reads are exactly
// 8 dwords/bank = conflict-free. Row 324 is an always-zero row used to feed
// K-step-1/quad-3 (k=56..63, i.e. the zero-pad region beyond stride 56).
// Weights: prep kernel writes wTb[tap][co:48][ci:64] bf16 (zero-padded) to ws;
// 55 KB, L2-resident, B-frags loaded per-lane as 16 B global loads.
// ---------------------------------------------------------------------------

typedef __attribute__((ext_vector_type(8))) short short8;
typedef __attribute__((ext_vector_type(4))) float f32x4;

#define XSTRIDE 56          // ushorts per x1 row (conflict-free for b128 reads)
#define ZROW    324         // always-zero row in x1
#define CSTRIDE 41          // floats per Cbuf pixel row (odd -> conflict-free b32)
#define WCI     64          // wTb ci stride (zero-padded 40->64)
#define WCO     48          // wTb co rows per tap (zero-padded 40->48)

static __device__ __forceinline__ unsigned short f2bf(float x) {
    unsigned int u = __float_as_uint(x);
    u += 0x7FFF + ((u >> 16) & 1);          // round-to-nearest-even
    return (unsigned short)(u >> 16);
}

static __device__ __forceinline__ float diff_round(float x) {
    const float TP = 6.2831853071795864769f;
    return x - sinf(x * TP) / TP;
}

template<int IN, int OUT>
static __device__ __forceinline__ void mlp_layer(const float* in,
                                                 const float* __restrict__ w,
                                                 const float* __restrict__ b,
                                                 float* out, bool do_relu) {
#pragma unroll
    for (int j = 0; j < OUT; ++j) {
        float a = b[j];
#pragma unroll
        for (int i = 0; i < IN; ++i) a = fmaf(in[i], w[i * OUT + j], a);
        out[j] = do_relu ? fmaxf(a, 0.f) : a;
    }
}

// ---------------------------------------------------------------------------
// Prep: w2 [tap][ci][co] fp32 -> wTb [tap][co:48][ci:64] bf16, zero-padded.
// ---------------------------------------------------------------------------
__global__ __launch_bounds__(256) void k_prep(const float* __restrict__ w2,
                                              unsigned short* __restrict__ wTb) {
    const int i = blockIdx.x * 256 + threadIdx.x;
    if (i >= 9 * WCO * WCI) return;
    const int ci  = i & (WCI - 1);
    const int tmp = i >> 6;                 // / WCI
    const int co  = tmp % WCO;
    const int tap = tmp / WCO;
    const float val = (co < 40 && ci < 40) ? w2[(tap * 40 + ci) * 40 + co] : 0.f;
    wTb[i] = f2bf(val);
}

// ---------------------------------------------------------------------------
// Kernel 1: per-patch token-build + conv1(fp32) + conv2(bf16 MFMA) + dense1.
// block = 256 threads (one per pixel), grid = 4096 patches.
// All register arrays constant-indexed (R2 lesson: one runtime index -> scratch).
// ---------------------------------------------------------------------------
__global__ __launch_bounds__(256, 2) void k_patch(
    const float* __restrict__ img, const float* __restrict__ lab,
    const float* __restrict__ msk,
    const float* __restrict__ w1, const float* __restrict__ b1,
    const unsigned short* __restrict__ wTb, const float* __restrict__ b2,
    const float* __restrict__ d1w, const float* __restrict__ d1b,
    float* __restrict__ nodes, float* __restrict__ lsv, float* __restrict__ agg)
{
    // sbuf: phase A = x1 bf16 [325][56] (36,400 B); phase B = Cbuf fp32 [256][41]
    __shared__ __align__(16) float sbuf[256 * CSTRIDE];   // 41,984 B
    __shared__ float p[18 * 18];
    __shared__ float red[4][2];
    __shared__ float wsum[4][6];
    unsigned short* x1 = (unsigned short*)sbuf;
    float* Cbuf = sbuf;

    const int n = blockIdx.x;
    const int t = threadIdx.x;
    const int g = n >> 10, cell = n & 1023;
    const int gi = cell >> 5, gj = cell & 31;
    const int sx = g & 1, sy = g >> 1;           // SHIFTS (0,0),(1,0),(0,1),(1,1)
    const int gx = sx + 2 * gi, gy = sy + 2 * gj;
    const int px0 = gx * 8 - 4, py0 = gy * 8 - 4;
    const float cid = (float)(gx * 64 + gy);

    const int u = t >> 4, v = t & 15;
    const int lane = t & 63, wv = t >> 6;
    const int lane15 = t & 15;                   // MFMA n / m-col index
    const int quad = (t >> 4) & 3;               // MFMA quad (lane>>4)

    // ---- phase 0: zero x1 (incl. pad cols 40..55, border rows, zero row) ----
    {
        unsigned int* x1w = (unsigned int*)x1;
        for (int i = t; i < 325 * XSTRIDE / 2; i += 256) x1w[i] = 0u;
        for (int i = t; i < 324; i += 256) p[i] = 0.f;
    }
    __syncthreads();

    // ---- phase 1: token + label stats ----
    const int r = px0 + u, c = py0 + v;
    const bool inr = (r >= 0) && (r < 512) && (c >= 0) && (c < 512);
    const float m  = inr ? msk[r * 512 + c] : -1.0f;
    const float f  = (m == cid) ? 1.f : 0.f;
    const float iv = inr ? img[r * 512 + c] : 0.f;
    const float lv = inr ? lab[r * 512 + c] : 0.f;
    p[(u + 1) * 18 + (v + 1)] = iv * f;

    float sf = f, slf = lv * f;
    for (int off = 32; off; off >>= 1) {
        sf  += __shfl_down(sf,  off);
        slf += __shfl_down(slf, off);
    }
    if (lane == 0) { red[wv][0] = sf; red[wv][1] = slf; }
    __syncthreads();

    // ---- phase 2: conv1 (1->40, fp32) -> relu -> bf16 -> x1 LDS ----
    {
        float nbv[9];
#pragma unroll
        for (int ky = 0; ky < 3; ++ky)
#pragma unroll
            for (int kx = 0; kx < 3; ++kx)
                nbv[ky * 3 + kx] = p[(u + ky) * 18 + (v + kx)];
        float a1[40];
#pragma unroll
        for (int co = 0; co < 40; ++co) a1[co] = b1[co];
#pragma unroll
        for (int k = 0; k < 9; ++k) {
            const float xv = nbv[k];
#pragma unroll
            for (int co = 0; co < 40; ++co)
                a1[co] = fmaf(xv, w1[k * 40 + co], a1[co]);
        }
        const int row = (u + 1) * 18 + (v + 1);
        unsigned int* x1w = (unsigned int*)x1;
#pragma unroll
        for (int cg = 0; cg < 20; ++cg) {
            const unsigned int lo = f2bf(fmaxf(a1[2 * cg], 0.f));
            const unsigned int hi = f2bf(fmaxf(a1[2 * cg + 1], 0.f));
            x1w[row * (XSTRIDE / 2) + cg] = lo | (hi << 16);
        }
    }
    if (t == 0) {
        const float SF = red[0][0] + red[1][0] + red[2][0] + red[3][0];
        const float SL = red[0][1] + red[1][1] + red[2][1] + red[3][1];
        lsv[n] = diff_round(diff_round(SL / (SF + 1e-8f)));
    }
    if (t < 10) agg[n * 10 + t] = 0.f;
    __syncthreads();

    // ---- phase 3: conv2 via bf16 MFMA, per-tap GEMM ----
    // wave wv handles pixels wv*64..wv*64+63 = 4 M-tiles of 16 (u = wv*4+mt).
    float bias[3];
#pragma unroll
    for (int nt = 0; nt < 3; ++nt) {
        const int co = nt * 16 + lane15;
        bias[nt] = (co < 40) ? b2[co] : 0.f;
    }
    f32x4 acc[4][3];
#pragma unroll
    for (int mt = 0; mt < 4; ++mt)
#pragma unroll
        for (int nt = 0; nt < 3; ++nt) {
            acc[mt][nt][0] = bias[nt]; acc[mt][nt][1] = bias[nt];
            acc[mt][nt][2] = bias[nt]; acc[mt][nt][3] = bias[nt];
        }

#pragma unroll
    for (int ky = 0; ky < 3; ++ky) {
#pragma unroll
        for (int kx = 0; kx < 3; ++kx) {
            const int tap = ky * 3 + kx;
            // B-frags: [k=ks*32+quad*8+j][n=co_base+lane15] from wTb[tap][co][ci]
            short8 bf[3][2];
#pragma unroll
            for (int nt = 0; nt < 3; ++nt)
#pragma unroll
                for (int ks = 0; ks < 2; ++ks)
                    bf[nt][ks] = *(const short8*)(wTb +
                        ((tap * WCO + nt * 16 + lane15) * WCI + ks * 32 + quad * 8));
#pragma unroll
            for (int mt = 0; mt < 4; ++mt) {
                // A row for pixel (u = wv*4+mt, v = lane15), tap (ky,kx):
                const int arow = (wv * 4 + mt + ky) * 18 + (lane15 + kx);
                const short8 a0 = *(const short8*)(x1 + (arow * XSTRIDE + quad * 8));
                const int i1 = (quad == 3) ? (ZROW * XSTRIDE)
                                           : (arow * XSTRIDE + 32 + quad * 8);
                const short8 a1f = *(const short8*)(x1 + i1);
#pragma unroll
                for (int nt = 0; nt < 3; ++nt) {
                    acc[mt][nt] = __builtin_amdgcn_mfma_f32_16x16x32_bf16(
                        a0, bf[nt][0], acc[mt][nt], 0, 0, 0);
                    acc[mt][nt] = __builtin_amdgcn_mfma_f32_16x16x32_bf16(
                        a1f, bf[nt][1], acc[mt][nt], 0, 0, 0);
                }
            }
        }
    }
    __syncthreads();   // all waves done reading x1 before Cbuf overwrites it

    // ---- phase 4: C writeback (relu) -> Cbuf[pixel][co], stride 41 ----
#pragma unroll
    for (int mt = 0; mt < 4; ++mt)
#pragma unroll
        for (int nt = 0; nt < 3; ++nt) {
            const int co = nt * 16 + lane15;
            if (co < 40) {
#pragma unroll
                for (int reg = 0; reg < 4; ++reg) {
                    const int pixel = wv * 64 + mt * 16 + quad * 4 + reg;
                    Cbuf[pixel * CSTRIDE + co] = fmaxf(acc[mt][nt][reg], 0.f);
                }
            }
        }
    __syncthreads();

    // ---- phase 5: dense1 partials + reduce ----
    float a6[6] = {0.f, 0.f, 0.f, 0.f, 0.f, 0.f};
    {
        const float* __restrict__ dw = d1w + t * 240;    // 40 co * 6 outputs
#pragma unroll
        for (int co = 0; co < 40; ++co) {
            const float a = Cbuf[t * CSTRIDE + co];      // already relu'd
#pragma unroll
            for (int k = 0; k < 6; ++k)
                a6[k] = fmaf(a, dw[co * 6 + k], a6[k]);
        }
    }
    for (int off = 32; off; off >>= 1) {
#pragma unroll
        for (int k = 0; k < 6; ++k) a6[k] += __shfl_down(a6[k], off);
    }
    if (lane == 0) {
#pragma unroll
        for (int k = 0; k < 6; ++k) wsum[wv][k] = a6[k];
    }
    __syncthreads();
    if (t < 6) {
        const float s = wsum[0][t] + wsum[1][t] + wsum[2][t] + wsum[3][t] + d1b[t];
        nodes[n * 6 + t] = fmaxf(s, 0.f);
    }
}

// ---------------------------------------------------------------------------
// Kernel 2: edge MLP + atomic segment-sum into agg
// ---------------------------------------------------------------------------
__global__ __launch_bounds__(256) void k_edge(
    const float* __restrict__ nodes, const int* __restrict__ snd,
    const int* __restrict__ rcv, int E,
    const float* __restrict__ we0, const float* __restrict__ be0,
    const float* __restrict__ we1, const float* __restrict__ be1,
    const float* __restrict__ we2, const float* __restrict__ be2,
    const float* __restrict__ we3, const float* __restrict__ be3,
    float* __restrict__ agg)
{
    const int e = blockIdx.x * 256 + threadIdx.x;
    if (e >= E) return;
    const int s = snd[e], r = rcv[e];
    float in[13];
#pragma unroll
    for (int i = 0; i < 6; ++i) in[i]     = nodes[s * 6 + i];
#pragma unroll
    for (int i = 0; i < 6; ++i) in[6 + i] = nodes[r * 6 + i];
    in[12] = 1.f;
    float h0[5], h1[5], h2[5], o[10];
    mlp_layer<13, 5>(in, we0, be0, h0, true);
    mlp_layer<5, 5>(h0, we1, be1, h1, true);
    mlp_layer<5, 5>(h1, we2, be2, h2, true);
    mlp_layer<5, 10>(h2, we3, be3, o, false);
#pragma unroll
    for (int j = 0; j < 10; ++j) atomicAdd(&agg[r * 10 + j], o[j]);
}

// ---------------------------------------------------------------------------
// Kernel 3: node MLP + logits + softmax cross-entropy
// ---------------------------------------------------------------------------
__global__ __launch_bounds__(256) void k_node(
    const float* __restrict__ nodes, const float* __restrict__ agg,
    const float* __restrict__ lsv,
    const float* __restrict__ wn0, const float* __restrict__ bn0,
    const float* __restrict__ wn1, const float* __restrict__ bn1,
    const float* __restrict__ wn2, const float* __restrict__ bn2,
    const float* __restrict__ wn3, const float* __restrict__ bn3,
    const float* __restrict__ wout, const float* __restrict__ bout,
    float* __restrict__ out, int N)
{
    const int n = blockIdx.x * 256 + threadIdx.x;
    if (n >= N) return;
    float in[17];
#pragma unroll
    for (int i = 0; i < 6; ++i)  in[i]     = nodes[n * 6 + i];
#pragma unroll
    for (int i = 0; i < 10; ++i) in[6 + i] = agg[n * 10 + i];
    in[16] = 1.f;
    float h0[5], h1[5], h2[5], o[10];
    mlp_layer<17, 5>(in, wn0, bn0, h0, true);
    mlp_layer<5, 5>(h0, wn1, bn1, h1, true);
    mlp_layer<5, 5>(h1, wn2, bn2, h2, true);
    mlp_layer<5, 10>(h2, wn3, bn3, o, false);

    float l0 = bout[0], l1 = bout[1];
#pragma unroll
    for (int i = 0; i < 10; ++i) {
        l0 = fmaf(o[i], wout[i * 2 + 0], l0);
        l1 = fmaf(o[i], wout[i * 2 + 1], l1);
    }
    const float mx  = fmaxf(l0, l1);
    const float e0  = expf(l0 - mx), e1 = expf(l1 - mx);
    const float lse = mx + logf(e0 + e1);
    const float sv  = lsv[n];
    out[n] = -((1.f - sv) * (l0 - lse) + sv * (l1 - lse));
}

// ---------------------------------------------------------------------------
extern "C" void kernel_launch(void* const* d_in, const int* in_sizes, int n_in,
                              void* d_out, int out_size, void* d_ws, size_t ws_size,
                              hipStream_t stream) {
    (void)n_in; (void)ws_size;
    const float* img = (const float*)d_in[0];
    const float* lab = (const float*)d_in[1];
    const float* msk = (const float*)d_in[2];
    const float* w1  = (const float*)d_in[3];
    const float* b1  = (const float*)d_in[4];
    const float* w2  = (const float*)d_in[5];
    const float* b2  = (const float*)d_in[6];
    const float* d1w = (const float*)d_in[7];
    const float* d1b = (const float*)d_in[8];
    const float* we0 = (const float*)d_in[9],  *be0 = (const float*)d_in[10];
    const float* we1 = (const float*)d_in[11], *be1 = (const float*)d_in[12];
    const float* we2 = (const float*)d_in[13], *be2 = (const float*)d_in[14];
    const float* we3 = (const float*)d_in[15], *be3 = (const float*)d_in[16];
    const float* wn0 = (const float*)d_in[17], *bn0 = (const float*)d_in[18];
    const float* wn1 = (const float*)d_in[19], *bn1 = (const float*)d_in[20];
    const float* wn2 = (const float*)d_in[21], *bn2 = (const float*)d_in[22];
    const float* wn3 = (const float*)d_in[23], *bn3 = (const float*)d_in[24];
    const float* wout = (const float*)d_in[25], *bout = (const float*)d_in[26];
    const int* snd = (const int*)d_in[27];
    const int* rcv = (const int*)d_in[28];
    const int E = in_sizes[27];
    const int N = out_size;              // 4096 nodes

    float* ws    = (float*)d_ws;
    float* nodes = ws;                   // N*6
    float* lsvb  = ws + (size_t)N * 6;   // N
    float* agg   = ws + (size_t)N * 7;   // N*10 (zeroed inside k_patch)
    unsigned short* wTb = (unsigned short*)(ws + (size_t)N * 17);  // 9*48*64 bf16
    float* out   = (float*)d_out;

    const int prep_n = 9 * WCO * WCI;
    k_prep<<<(prep_n + 255) / 256, 256, 0, stream>>>(w2, wTb);
    k_patch<<<N, 256, 0, stream>>>(img, lab, msk, w1, b1, wTb, b2, d1w, d1b,
                                   nodes, lsvb, agg);
    k_edge<<<(E + 255) / 256, 256, 0, stream>>>(nodes, snd, rcv, E,
                                                we0, be0, we1, be1, we2, be2,
                                                we3, be3, agg);
    k_node<<<(N + 255) / 256, 256, 0, stream>>>(nodes, agg, lsvb,
                                                wn0, bn0, wn1, bn1, wn2, bn2,
                                                wn3, bn3, wout, bout, out, N);
}